// Round 15
// baseline (208.136 us; speedup 1.0000x reference)
//
#include <hip/hip_runtime.h>
#include <hip/hip_bf16.h>
#include <math.h>

typedef short bf16x8 __attribute__((ext_vector_type(8)));
typedef float f32x4 __attribute__((ext_vector_type(4)));

static __device__ __forceinline__ unsigned short f2bf(float f) {
  unsigned int u = __float_as_uint(f);
  u += 0x7FFFu + ((u >> 16) & 1u);
  return (unsigned short)(u >> 16);
}

// async global->LDS, 16B per lane; dest = wave-uniform base + lane*16
static __device__ __forceinline__ void gload16(const unsigned short* g, unsigned short* l) {
  __builtin_amdgcn_global_load_lds(
      (const __attribute__((address_space(1))) unsigned int*)g,
      (__attribute__((address_space(3))) unsigned int*)l, 16, 0, 0);
}

// ---------------- K0: W (f32 [h][k][e]) -> bf16 transposed wt[j][k], j = s*768+h*64+e ----
__global__ __launch_bounds__(256) void k_prep_w(const float* __restrict__ Wq,
                                                const float* __restrict__ Wk,
                                                const float* __restrict__ Wv,
                                                unsigned short* __restrict__ wt) {
  __shared__ unsigned short lw[64][72];
  int sh = blockIdx.x;
  int kt = blockIdx.y;
  int s = sh / 12, h = sh - s * 12;
  const float* W = (s == 0 ? Wq : (s == 1 ? Wk : Wv)) + h * 49152 + (kt << 6) * 64;
  int tid = threadIdx.x;
#pragma unroll
  for (int it = 0; it < 4; ++it) {
    int idx = it * 256 + tid;
    int kk = idx >> 4, e4 = (idx & 15) << 2;
    float4 v = *(const float4*)(W + kk * 64 + e4);
    lw[e4 + 0][kk] = f2bf(v.x);
    lw[e4 + 1][kk] = f2bf(v.y);
    lw[e4 + 2][kk] = f2bf(v.z);
    lw[e4 + 3][kk] = f2bf(v.w);
  }
  __syncthreads();
  unsigned short* outp = wt + sh * 49152 + (kt << 6);
#pragma unroll
  for (int it = 0; it < 2; ++it) {
    int c = it * 256 + tid;
    int e = c >> 3, kc = (c & 7) << 3;
    *(uint4*)(outp + e * 768 + kc) = *(const uint4*)&lw[e][kc];
  }
}

// ---------------- K1: t = 2*x_tok + pe (bf16); PE computed once, reused over 16 batches ----
__global__ __launch_bounds__(256) void k_build_t(const float* __restrict__ x,
                                                 unsigned short* __restrict__ t) {
  int g = blockIdx.x * 256 + threadIdx.x;      // 98304 threads, 8 elems x 16 batches
  int f = g << 3;
  int m  = f / 768;
  int d  = f - m * 768;
  int c  = f >> 18;
  int rl = f & 262143;
  int n  = rl >> 8;
  int qq = rl & 255;
  int ii = qq >> 4, jj = qq & 15;
  float pe8[8];
#pragma unroll
  for (int u = 0; u < 8; ++u) {
    int dd = d + u;
    int k = dd >> 1;
    float ang = (float)m * expf(-0.023985261385f * (float)k);
    pe8[u] = (dd & 1) ? cosf(ang) : sinf(ang);
  }
  const float* xp0 = x + (c << 18) + (((n >> 5) << 4) + ii) * 512 + ((n & 31) << 4) + jj;
  for (int b = 0; b < 16; ++b) {
    const float* xp = xp0 + b * 786432;
    float4 v0 = *(const float4*)xp;
    float4 v1 = *(const float4*)(xp + 4);
    float xv[8] = {v0.x, v0.y, v0.z, v0.w, v1.x, v1.y, v1.z, v1.w};
    unsigned short tmp[8];
#pragma unroll
    for (int u = 0; u < 8; ++u) tmp[u] = f2bf(2.0f * xv[u] + pe8[u]);
    *(uint4*)(t + b * 786432 + f) = *(const uint4*)tmp;
  }
}

// ---- K2: dense GEMM 16384x768x2304, 128x128, BK=32, 4-buf depth-2 counted-vmcnt pipe ----
union SMQ {
  struct { unsigned short A[4][128][32]; unsigned short B[4][128][32]; } g;  // 64 KB
  unsigned short tr[64][140];
};
#define QKV_STEP(BUF)                                                                   \
  {                                                                                     \
    bf16x8 a[4], b[4];                                                                  \
    _Pragma("unroll") for (int mi = 0; mi < 4; ++mi)                                    \
        a[mi] = *(const bf16x8*)&sm.g.A[BUF][wm * 64 + mi * 16 + q16][g << 3];          \
    _Pragma("unroll") for (int ni = 0; ni < 4; ++ni)                                    \
        b[ni] = *(const bf16x8*)&sm.g.B[BUF][wn * 64 + ni * 16 + q16][g << 3];          \
    _Pragma("unroll") for (int mi = 0; mi < 4; ++mi)                                    \
        _Pragma("unroll") for (int ni = 0; ni < 4; ++ni)                                \
            acc[mi][ni] =                                                               \
                __builtin_amdgcn_mfma_f32_16x16x32_bf16(a[mi], b[ni], acc[mi][ni], 0, 0, 0); \
  }
#define STAGE(KT, BUF)                                                                  \
  gload16(gA0 + (KT) * 32, &sm.g.A[BUF][32 * w][0]);                                    \
  gload16(gA1 + (KT) * 32, &sm.g.A[BUF][32 * w + 16][0]);                               \
  gload16(gB0 + (KT) * 32, &sm.g.B[BUF][32 * w][0]);                                    \
  gload16(gB1 + (KT) * 32, &sm.g.B[BUF][32 * w + 16][0]);
#define WAITV(N) asm volatile("s_waitcnt vmcnt(" #N ")" ::: "memory")
#define BARRIER() __builtin_amdgcn_s_barrier()
#define SBAR() __builtin_amdgcn_sched_barrier(0)
__global__ __launch_bounds__(256) void k_qkv(
    const unsigned short* __restrict__ t, const unsigned short* __restrict__ wt,
    const float* __restrict__ bq, const float* __restrict__ bk, const float* __restrict__ bv,
    unsigned short* __restrict__ qout, unsigned short* __restrict__ kout,
    unsigned short* __restrict__ vout) {
  __shared__ SMQ sm;
  int bid = blockIdx.x;                   // 2304 blocks; 18 same-rt blocks co-XCD
  int xcd = bid & 7, idx = bid >> 3;      // idx 0..287
  int rt = xcd * 16 + idx / 18;
  int jt = idx % 18;
  int row0 = rt << 7;
  int j0 = jt << 7;
  int s = jt / 6;
  int h0 = (jt % 6) * 2;
  const float* bias = (s == 0 ? bq : (s == 1 ? bk : bv));
  unsigned short* outp = (s == 0 ? qout : (s == 1 ? kout : vout));
  int tid = threadIdx.x, lane = tid & 63, w = tid >> 6;
  int wm = w >> 1, wn = w & 1;
  int g = lane >> 4, q16 = lane & 15;
  const unsigned short* gA0 = t  + (row0 + 32 * w + (lane >> 2)) * 768 + ((lane & 3) << 3);
  const unsigned short* gA1 = gA0 + 16 * 768;
  const unsigned short* gB0 = wt + (j0 + 32 * w + (lane >> 2)) * 768 + ((lane & 3) << 3);
  const unsigned short* gB1 = gB0 + 16 * 768;
  f32x4 acc[4][4] = {};
  // prologue: stage tiles 0,1
  STAGE(0, 0);
  STAGE(1, 1);
  // main loop: tiles 0..19, depth-2 prefetch, vmcnt(8) = 2 tiles (8 loads) stay in flight
  for (int it = 0; it < 5; ++it) {
    int kb = it * 4;
    STAGE(kb + 2, 2); WAITV(8); BARRIER(); SBAR(); QKV_STEP(0);
    STAGE(kb + 3, 3); WAITV(8); BARRIER(); SBAR(); QKV_STEP(1);
    STAGE(kb + 4, 0); WAITV(8); BARRIER(); SBAR(); QKV_STEP(2);
    STAGE(kb + 5, 1); WAITV(8); BARRIER(); SBAR(); QKV_STEP(3);
  }
  // tail: tiles 20..23
  STAGE(22, 2); WAITV(8); BARRIER(); SBAR(); QKV_STEP(0);   // tile 20
  STAGE(23, 3); WAITV(8); BARRIER(); SBAR(); QKV_STEP(1);   // tile 21
  WAITV(4); BARRIER(); SBAR(); QKV_STEP(2);                 // tile 22
  WAITV(0); BARRIER(); SBAR(); QKV_STEP(3);                 // tile 23
  int bb2 = row0 >> 10, n0 = row0 & 1023;
  if (s < 2) {
    // q: fold 1/sqrt(64) * log2(e) so attention works in exp2 domain
    float qs = (s == 0) ? 0.18033688011f : 1.0f;
#pragma unroll
    for (int ni = 0; ni < 4; ++ni) {
      int colg = wn * 64 + ni * 16 + q16;
      int h = h0 + (colg >> 6);
      int e = colg & 63;
      float be = bias[h * 64 + e];
      int base = (bb2 * 12 + h) << 16;
#pragma unroll
      for (int mi = 0; mi < 4; ++mi)
#pragma unroll
        for (int r = 0; r < 4; ++r) {
          int n = n0 + wm * 64 + mi * 16 + (g << 2) + r;
          outp[base + (n << 6) + e] = f2bf((acc[mi][ni][r] + be) * qs);
        }
    }
  } else {
    // V: store transposed [b][h][e][n'], kv-index permuted within each 32-block:
    // position p holds original o, p(o) = ((o>>2)&3)*8 + ((o>>4)&1)*4 + (o&3),
    // so k_attn's P-registers are directly the PV A-fragment.
#pragma unroll
    for (int hh = 0; hh < 2; ++hh) {
      __syncthreads();
      if (wn == hh) {
#pragma unroll
        for (int ni = 0; ni < 4; ++ni) {
          int e = ni * 16 + q16;
          float be = bias[(h0 + hh) * 64 + e];
#pragma unroll
          for (int mi = 0; mi < 4; ++mi)
#pragma unroll
            for (int rp = 0; rp < 2; ++rp) {
              int rr = (wm * 2 + (mi >> 1)) * 32 + g * 8 + (mi & 1) * 4 + rp * 2;
              unsigned int lo = f2bf(acc[mi][ni][rp * 2] + be);
              unsigned int hi = f2bf(acc[mi][ni][rp * 2 + 1] + be);
              *(unsigned int*)&sm.tr[e][rr] = lo | (hi << 16);
            }
        }
      }
      __syncthreads();
      int base = (bb2 * 12 + h0 + hh) << 16;
#pragma unroll
      for (int it = 0; it < 4; ++it) {
        int c = it * 256 + tid;
        int e = c >> 4, nc = (c & 15) << 3;
        *(uint4*)(vout + base + (e << 10) + n0 + nc) = *(const uint4*)&sm.tr[e][nc];
      }
    }
  }
}

// ---- K3: flash attention, QBLK=64: 4 waves x 16 q-rows (state-halved round-9 text) ----
__global__ __launch_bounds__(256) void k_attn(
    const unsigned short* __restrict__ Q,
    const unsigned short* __restrict__ K,
    const unsigned short* __restrict__ Vg,   // transposed+permuted [b][h][e][n']
    float* __restrict__ out) {
  __shared__ unsigned short Kt[64][72];      // [kv][k]
  __shared__ unsigned short Vt[80][72];      // [e][kv']; rows 64..79: ones-column block
  int bid = blockIdx.x;                      // 3072 blocks; same-(b,h) co-XCD, qt in low bits
  int xcd = bid & 7, idx = bid >> 3;         // idx 0..383
  int bh = xcd * 24 + (idx >> 4);
  int qt = idx & 15;                         // 16 q-tiles of 64 rows
  int b = bh / 12, h = bh - b * 12;
  int tid = threadIdx.x, lane = tid & 63, w = tid >> 6;
  int g = lane >> 4, q16 = lane & 15;
  int base = bh << 16;
  const unsigned short* Qp = Q + base + (qt << 6) * 64;
  const unsigned short* Kp = K + base;
  const unsigned short* Vp = Vg + base;
  {                                          // ones-column block init (once)
    int rr = 64 + (tid >> 4), c4 = (tid & 15) << 2;
    ushort4 z = {0, 0, 0, 0};
    if ((tid >> 4) == 0) { z.x = z.y = z.z = z.w = 0x3F80; }
    *(ushort4*)&Vt[rr][c4] = z;
  }
  bf16x8 qa[2];
#pragma unroll
  for (int kf = 0; kf < 2; ++kf)
    qa[kf] = *(const bf16x8*)(Qp + (w * 16 + q16) * 64 + kf * 32 + (g << 3));
  f32x4 o[5] = {};                           // cb=4 accumulates row-sums (l)
  float mrow = -1e30f;
  for (int kv0 = 0; kv0 < 1024; kv0 += 64) {
    __syncthreads();
#pragma unroll
    for (int it = 0; it < 2; ++it) {
      int idx2 = it * 256 + tid;
      int rr = idx2 >> 3, cc = (idx2 & 7) << 3;
      *(uint4*)&Kt[rr][cc] = *(const uint4*)(Kp + (kv0 << 6) + (idx2 << 3));
      *(uint4*)&Vt[rr][cc] = *(const uint4*)(Vp + (rr << 10) + kv0 + cc);
    }
    __syncthreads();
    // S^T = K Q^T : lane owns q=q16, kv = cb*16 + g*4 + r
    f32x4 s[4] = {};
#pragma unroll
    for (int cb = 0; cb < 4; ++cb) {
      bf16x8 ka0 = *(const bf16x8*)&Kt[cb * 16 + q16][g << 3];
      bf16x8 ka1 = *(const bf16x8*)&Kt[cb * 16 + q16][32 + (g << 3)];
      s[cb] = __builtin_amdgcn_mfma_f32_16x16x32_bf16(ka0, qa[0], s[cb], 0, 0, 0);
      s[cb] = __builtin_amdgcn_mfma_f32_16x16x32_bf16(ka1, qa[1], s[cb], 0, 0, 0);
    }
    // row max (15 fmax + 2 shfl), defer-max rescale
    float mx = s[0][0];
#pragma unroll
    for (int cb = 0; cb < 4; ++cb)
#pragma unroll
      for (int r = 0; r < 4; ++r) mx = fmaxf(mx, s[cb][r]);
    mx = fmaxf(mx, __shfl_xor(mx, 16));
    mx = fmaxf(mx, __shfl_xor(mx, 32));
    if (__any(mx > mrow + 8.f)) {
      float mnew = fmaxf(mrow, mx);
      float sc = __builtin_amdgcn_exp2f(mrow - mnew);
      mrow = mnew;
#pragma unroll
      for (int r = 0; r < 4; ++r) {
        float scr = __shfl(sc, (g << 2) + r);   // map softmax-domain -> o-domain rows
#pragma unroll
        for (int cb = 0; cb < 5; ++cb) o[cb][r] *= scr;
      }
    }
    // P = exp2(s - m), packed to bf16 pairs in-register
    unsigned int pk[4][2];
#pragma unroll
    for (int cb = 0; cb < 4; ++cb)
#pragma unroll
      for (int j2 = 0; j2 < 2; ++j2) {
        float plo = __builtin_amdgcn_exp2f(s[cb][2 * j2] - mrow);
        float phi = __builtin_amdgcn_exp2f(s[cb][2 * j2 + 1] - mrow);
        asm("v_cvt_pk_bf16_f32 %0, %1, %2" : "=v"(pk[cb][j2]) : "v"(plo), "v"(phi));
      }
    // O += P V : V's kv-order is permuted so lane's own pk registers ARE the A-fragment
#pragma unroll
    for (int kk = 0; kk < 2; ++kk) {
      union { unsigned int u[4]; bf16x8 v; } pa;
      pa.u[0] = pk[2 * kk][0];
      pa.u[1] = pk[2 * kk][1];
      pa.u[2] = pk[2 * kk + 1][0];
      pa.u[3] = pk[2 * kk + 1][1];
#pragma unroll
      for (int cb = 0; cb < 5; ++cb) {
        bf16x8 vb = *(const bf16x8*)&Vt[cb * 16 + q16][kk * 32 + (g << 3)];
        o[cb] = __builtin_amdgcn_mfma_f32_16x16x32_bf16(pa.v, vb, o[cb], 0, 0, 0);
      }
    }
  }
  // epilogue: l = o[4] (col 64), broadcast within 4-lane group; scatter untokenized
#pragma unroll
  for (int r = 0; r < 4; ++r) {
    float lr = __shfl(o[4][r], lane & 48);
    float inv = 1.0f / lr;
    int m = (qt << 6) + w * 16 + (g << 2) + r;
#pragma unroll
    for (int cb = 0; cb < 4; ++cb) {
      int d = (h << 6) + cb * 16 + q16;
      int f = m * 768 + d;
      int c = f >> 18, rl = f & 262143, n = rl >> 8, qq = rl & 255;
      out[((b * 3 + c) << 18) + (((n >> 5) << 4) + (qq >> 4)) * 512 + ((n & 31) << 4) + (qq & 15)] =
          o[cb][r] * inv;
    }
  }
}

extern "C" void kernel_launch(void* const* d_in, const int* in_sizes, int n_in,
                              void* d_out, int out_size, void* d_ws, size_t ws_size,
                              hipStream_t stream) {
  const float* x  = (const float*)d_in[0];
  const float* Wq = (const float*)d_in[1];
  const float* bq = (const float*)d_in[2];
  const float* Wk = (const float*)d_in[3];
  const float* bk = (const float*)d_in[4];
  const float* Wv = (const float*)d_in[5];
  const float* bv = (const float*)d_in[6];
  float* out = (float*)d_out;
  unsigned short* wt = (unsigned short*)d_ws;
  unsigned short* t  = wt + 1769472;
  unsigned short* qw = t  + 12582912;
  unsigned short* kw = qw + 12582912;
  unsigned short* vw = kw + 12582912;
  k_prep_w<<<dim3(36, 12), 256, 0, stream>>>(Wq, Wk, Wv, wt);
  k_build_t<<<384, 256, 0, stream>>>(x, t);
  k_qkv<<<2304, 256, 0, stream>>>(t, wt, bq, bk, bv, qw, kw, vw);
  k_attn<<<3072, 256, 0, stream>>>(qw, kw, vw, out);
}

// Round 17
// 181.397 us; speedup vs baseline: 1.1474x; 1.1474x over previous
//
#include <hip/hip_runtime.h>
#include <hip/hip_bf16.h>
#include <math.h>

typedef short bf16x8 __attribute__((ext_vector_type(8)));
typedef float f32x4 __attribute__((ext_vector_type(4)));

static __device__ __forceinline__ unsigned short f2bf(float f) {
  unsigned int u = __float_as_uint(f);
  u += 0x7FFFu + ((u >> 16) & 1u);
  return (unsigned short)(u >> 16);
}

// async global->LDS, 16B per lane; dest = wave-uniform base + lane*16
static __device__ __forceinline__ void gload16(const unsigned short* g, unsigned short* l) {
  __builtin_amdgcn_global_load_lds(
      (const __attribute__((address_space(1))) unsigned int*)g,
      (__attribute__((address_space(3))) unsigned int*)l, 16, 0, 0);
}

// ---------------- K0: W (f32 [h][k][e]) -> bf16 transposed wt[j][k], j = s*768+h*64+e ----
__global__ __launch_bounds__(256) void k_prep_w(const float* __restrict__ Wq,
                                                const float* __restrict__ Wk,
                                                const float* __restrict__ Wv,
                                                unsigned short* __restrict__ wt) {
  __shared__ unsigned short lw[64][72];
  int sh = blockIdx.x;
  int kt = blockIdx.y;
  int s = sh / 12, h = sh - s * 12;
  const float* W = (s == 0 ? Wq : (s == 1 ? Wk : Wv)) + h * 49152 + (kt << 6) * 64;
  int tid = threadIdx.x;
#pragma unroll
  for (int it = 0; it < 4; ++it) {
    int idx = it * 256 + tid;
    int kk = idx >> 4, e4 = (idx & 15) << 2;
    float4 v = *(const float4*)(W + kk * 64 + e4);
    lw[e4 + 0][kk] = f2bf(v.x);
    lw[e4 + 1][kk] = f2bf(v.y);
    lw[e4 + 2][kk] = f2bf(v.z);
    lw[e4 + 3][kk] = f2bf(v.w);
  }
  __syncthreads();
  unsigned short* outp = wt + sh * 49152 + (kt << 6);
#pragma unroll
  for (int it = 0; it < 2; ++it) {
    int c = it * 256 + tid;
    int e = c >> 3, kc = (c & 7) << 3;
    *(uint4*)(outp + e * 768 + kc) = *(const uint4*)&lw[e][kc];
  }
}

// ---- K1: t = 2*x_tok + pe (bf16); PE computed once per thread, 4 batches per block ----
__global__ __launch_bounds__(256) void k_build_t(const float* __restrict__ x,
                                                 unsigned short* __restrict__ t) {
  int bid = blockIdx.x;                        // 1536 = 384 f-chunks x 4 batch-chunks
  int bchunk = bid & 3;
  int g = (bid >> 2) * 256 + threadIdx.x;      // 98304 f-positions, 8 elems each
  int f = g << 3;
  int m  = f / 768;
  int d  = f - m * 768;
  int c  = f >> 18;
  int rl = f & 262143;
  int n  = rl >> 8;
  int qq = rl & 255;
  int ii = qq >> 4, jj = qq & 15;
  float pe8[8];
#pragma unroll
  for (int u = 0; u < 8; ++u) {
    int dd = d + u;
    int k = dd >> 1;
    float ang = (float)m * expf(-0.023985261385f * (float)k);
    pe8[u] = (dd & 1) ? cosf(ang) : sinf(ang);
  }
  const float* xp0 = x + (c << 18) + (((n >> 5) << 4) + ii) * 512 + ((n & 31) << 4) + jj;
  for (int b = bchunk * 4; b < bchunk * 4 + 4; ++b) {
    const float* xp = xp0 + b * 786432;
    float4 v0 = *(const float4*)xp;
    float4 v1 = *(const float4*)(xp + 4);
    float xv[8] = {v0.x, v0.y, v0.z, v0.w, v1.x, v1.y, v1.z, v1.w};
    unsigned short tmp[8];
#pragma unroll
    for (int u = 0; u < 8; ++u) tmp[u] = f2bf(2.0f * xv[u] + pe8[u]);
    *(uint4*)(t + b * 786432 + f) = *(const uint4*)tmp;
  }
}

// ---- K2: dense GEMM 16384x768x2304, 128x128, BK=32, 4-buf depth-2 counted-vmcnt pipe ----
union SMQ {
  struct { unsigned short A[4][128][32]; unsigned short B[4][128][32]; } g;  // 64 KB
  unsigned short tr[64][140];
};
#define QKV_STEP(BUF)                                                                   \
  {                                                                                     \
    bf16x8 a[4], b[4];                                                                  \
    _Pragma("unroll") for (int mi = 0; mi < 4; ++mi)                                    \
        a[mi] = *(const bf16x8*)&sm.g.A[BUF][wm * 64 + mi * 16 + q16][g << 3];          \
    _Pragma("unroll") for (int ni = 0; ni < 4; ++ni)                                    \
        b[ni] = *(const bf16x8*)&sm.g.B[BUF][wn * 64 + ni * 16 + q16][g << 3];          \
    _Pragma("unroll") for (int mi = 0; mi < 4; ++mi)                                    \
        _Pragma("unroll") for (int ni = 0; ni < 4; ++ni)                                \
            acc[mi][ni] =                                                               \
                __builtin_amdgcn_mfma_f32_16x16x32_bf16(a[mi], b[ni], acc[mi][ni], 0, 0, 0); \
  }
#define STAGE(KT, BUF)                                                                  \
  gload16(gA0 + (KT) * 32, &sm.g.A[BUF][32 * w][0]);                                    \
  gload16(gA1 + (KT) * 32, &sm.g.A[BUF][32 * w + 16][0]);                               \
  gload16(gB0 + (KT) * 32, &sm.g.B[BUF][32 * w][0]);                                    \
  gload16(gB1 + (KT) * 32, &sm.g.B[BUF][32 * w + 16][0]);
#define WAITV(N) asm volatile("s_waitcnt vmcnt(" #N ")" ::: "memory")
#define BARRIER() __builtin_amdgcn_s_barrier()
#define SBAR() __builtin_amdgcn_sched_barrier(0)
__global__ __launch_bounds__(256) void k_qkv(
    const unsigned short* __restrict__ t, const unsigned short* __restrict__ wt,
    const float* __restrict__ bq, const float* __restrict__ bk, const float* __restrict__ bv,
    unsigned short* __restrict__ qout, unsigned short* __restrict__ kout,
    unsigned short* __restrict__ vout) {
  __shared__ SMQ sm;
  int bid = blockIdx.x;                   // 2304 blocks; 18 same-rt blocks co-XCD
  int xcd = bid & 7, idx = bid >> 3;      // idx 0..287
  int rt = xcd * 16 + idx / 18;
  int jt = idx % 18;
  int row0 = rt << 7;
  int j0 = jt << 7;
  int s = jt / 6;
  int h0 = (jt % 6) * 2;
  const float* bias = (s == 0 ? bq : (s == 1 ? bk : bv));
  unsigned short* outp = (s == 0 ? qout : (s == 1 ? kout : vout));
  int tid = threadIdx.x, lane = tid & 63, w = tid >> 6;
  int wm = w >> 1, wn = w & 1;
  int g = lane >> 4, q16 = lane & 15;
  const unsigned short* gA0 = t  + (row0 + 32 * w + (lane >> 2)) * 768 + ((lane & 3) << 3);
  const unsigned short* gA1 = gA0 + 16 * 768;
  const unsigned short* gB0 = wt + (j0 + 32 * w + (lane >> 2)) * 768 + ((lane & 3) << 3);
  const unsigned short* gB1 = gB0 + 16 * 768;
  f32x4 acc[4][4] = {};
  // prologue: stage tiles 0,1
  STAGE(0, 0);
  STAGE(1, 1);
  // main loop: tiles 0..19, depth-2 prefetch, vmcnt(8) = 2 tiles (8 loads) stay in flight
  for (int it = 0; it < 5; ++it) {
    int kb = it * 4;
    STAGE(kb + 2, 2); WAITV(8); BARRIER(); SBAR(); QKV_STEP(0);
    STAGE(kb + 3, 3); WAITV(8); BARRIER(); SBAR(); QKV_STEP(1);
    STAGE(kb + 4, 0); WAITV(8); BARRIER(); SBAR(); QKV_STEP(2);
    STAGE(kb + 5, 1); WAITV(8); BARRIER(); SBAR(); QKV_STEP(3);
  }
  // tail: tiles 20..23
  STAGE(22, 2); WAITV(8); BARRIER(); SBAR(); QKV_STEP(0);   // tile 20
  STAGE(23, 3); WAITV(8); BARRIER(); SBAR(); QKV_STEP(1);   // tile 21
  WAITV(4); BARRIER(); SBAR(); QKV_STEP(2);                 // tile 22
  WAITV(0); BARRIER(); SBAR(); QKV_STEP(3);                 // tile 23
  int bb2 = row0 >> 10, n0 = row0 & 1023;
  if (s < 2) {
    // q: fold 1/sqrt(64) * log2(e) so attention works in exp2 domain
    float qs = (s == 0) ? 0.18033688011f : 1.0f;
#pragma unroll
    for (int ni = 0; ni < 4; ++ni) {
      int colg = wn * 64 + ni * 16 + q16;
      int h = h0 + (colg >> 6);
      int e = colg & 63;
      float be = bias[h * 64 + e];
      int base = (bb2 * 12 + h) << 16;
#pragma unroll
      for (int mi = 0; mi < 4; ++mi)
#pragma unroll
        for (int r = 0; r < 4; ++r) {
          int n = n0 + wm * 64 + mi * 16 + (g << 2) + r;
          outp[base + (n << 6) + e] = f2bf((acc[mi][ni][r] + be) * qs);
        }
    }
  } else {
    // V: store transposed [b][h][e][n'], kv-index permuted within each 32-block:
    // position p holds original o, p(o) = ((o>>2)&3)*8 + ((o>>4)&1)*4 + (o&3),
    // so k_attn's P-registers are directly the PV A-fragment.
#pragma unroll
    for (int hh = 0; hh < 2; ++hh) {
      __syncthreads();
      if (wn == hh) {
#pragma unroll
        for (int ni = 0; ni < 4; ++ni) {
          int e = ni * 16 + q16;
          float be = bias[(h0 + hh) * 64 + e];
#pragma unroll
          for (int mi = 0; mi < 4; ++mi)
#pragma unroll
            for (int rp = 0; rp < 2; ++rp) {
              int rr = (wm * 2 + (mi >> 1)) * 32 + g * 8 + (mi & 1) * 4 + rp * 2;
              unsigned int lo = f2bf(acc[mi][ni][rp * 2] + be);
              unsigned int hi = f2bf(acc[mi][ni][rp * 2 + 1] + be);
              *(unsigned int*)&sm.tr[e][rr] = lo | (hi << 16);
            }
        }
      }
      __syncthreads();
      int base = (bb2 * 12 + h0 + hh) << 16;
#pragma unroll
      for (int it = 0; it < 4; ++it) {
        int c = it * 256 + tid;
        int e = c >> 4, nc = (c & 15) << 3;
        *(uint4*)(vout + base + (e << 10) + n0 + nc) = *(const uint4*)&sm.tr[e][nc];
      }
    }
  }
}

// ---------------- K3: flash attention, swapped QK^T + in-register softmax (round-13) ----
__global__ __launch_bounds__(256) void k_attn(
    const unsigned short* __restrict__ Q,
    const unsigned short* __restrict__ K,
    const unsigned short* __restrict__ Vg,   // transposed+permuted [b][h][e][n']
    float* __restrict__ out) {
  __shared__ unsigned short Kt[64][72];      // [kv][k]
  __shared__ unsigned short Vt[80][72];      // [e][kv']; rows 64..79: ones-column block
  int bid = blockIdx.x;                      // 1536 blocks; same-(b,h) co-XCD
  int xcd = bid & 7, idx = bid >> 3;
  int bh = xcd * 24 + (idx >> 3);
  int qt = idx & 7;
  int b = bh / 12, h = bh - b * 12;
  int tid = threadIdx.x, lane = tid & 63, w = tid >> 6;
  int g = lane >> 4, q16 = lane & 15;
  int base = bh << 16;
  const unsigned short* Qp = Q + base + (qt << 7) * 64;
  const unsigned short* Kp = K + base;
  const unsigned short* Vp = Vg + base;
  {                                          // ones-column block init (once)
    int rr = 64 + (tid >> 4), c4 = (tid & 15) << 2;
    ushort4 z = {0, 0, 0, 0};
    if ((tid >> 4) == 0) { z.x = z.y = z.z = z.w = 0x3F80; }
    *(ushort4*)&Vt[rr][c4] = z;
  }
  bf16x8 qa[2][2];
#pragma unroll
  for (int mt = 0; mt < 2; ++mt)
#pragma unroll
    for (int kf = 0; kf < 2; ++kf)
      qa[mt][kf] = *(const bf16x8*)(Qp + (w * 32 + mt * 16 + q16) * 64 + kf * 32 + (g << 3));
  f32x4 o[2][5] = {};                        // cb=4 accumulates row-sums (l)
  float mrow[2] = {-1e30f, -1e30f};
  for (int kv0 = 0; kv0 < 1024; kv0 += 64) {
    __syncthreads();
#pragma unroll
    for (int it = 0; it < 2; ++it) {
      int idx2 = it * 256 + tid;
      int rr = idx2 >> 3, cc = (idx2 & 7) << 3;
      *(uint4*)&Kt[rr][cc] = *(const uint4*)(Kp + (kv0 << 6) + (idx2 << 3));
      *(uint4*)&Vt[rr][cc] = *(const uint4*)(Vp + (rr << 10) + kv0 + cc);
    }
    __syncthreads();
    // S^T = K Q^T : lane owns q=q16, kv = cb*16 + g*4 + r
    f32x4 s[2][4] = {};
#pragma unroll
    for (int cb = 0; cb < 4; ++cb) {
      bf16x8 ka0 = *(const bf16x8*)&Kt[cb * 16 + q16][g << 3];
      bf16x8 ka1 = *(const bf16x8*)&Kt[cb * 16 + q16][32 + (g << 3)];
#pragma unroll
      for (int mt = 0; mt < 2; ++mt) {
        s[mt][cb] = __builtin_amdgcn_mfma_f32_16x16x32_bf16(ka0, qa[mt][0], s[mt][cb], 0, 0, 0);
        s[mt][cb] = __builtin_amdgcn_mfma_f32_16x16x32_bf16(ka1, qa[mt][1], s[mt][cb], 0, 0, 0);
      }
    }
    // row max (15 fmax + 2 shfl), defer-max rescale
    float pmax[2];
#pragma unroll
    for (int mt = 0; mt < 2; ++mt) {
      float mx = s[mt][0][0];
#pragma unroll
      for (int cb = 0; cb < 4; ++cb)
#pragma unroll
        for (int r = 0; r < 4; ++r) mx = fmaxf(mx, s[mt][cb][r]);
      mx = fmaxf(mx, __shfl_xor(mx, 16));
      mx = fmaxf(mx, __shfl_xor(mx, 32));
      pmax[mt] = mx;
    }
    if (__any((pmax[0] > mrow[0] + 8.f) || (pmax[1] > mrow[1] + 8.f))) {
#pragma unroll
      for (int mt = 0; mt < 2; ++mt) {
        float mnew = fmaxf(mrow[mt], pmax[mt]);
        float sc = __builtin_amdgcn_exp2f(mrow[mt] - mnew);
        mrow[mt] = mnew;
#pragma unroll
        for (int r = 0; r < 4; ++r) {
          float scr = __shfl(sc, (g << 2) + r);   // map softmax-domain -> o-domain rows
#pragma unroll
          for (int cb = 0; cb < 5; ++cb) o[mt][cb][r] *= scr;
        }
      }
    }
    // P = exp2(s - m), packed to bf16 pairs in-register
    unsigned int pk[2][4][2];
#pragma unroll
    for (int mt = 0; mt < 2; ++mt)
#pragma unroll
      for (int cb = 0; cb < 4; ++cb)
#pragma unroll
        for (int j2 = 0; j2 < 2; ++j2) {
          float plo = __builtin_amdgcn_exp2f(s[mt][cb][2 * j2] - mrow[mt]);
          float phi = __builtin_amdgcn_exp2f(s[mt][cb][2 * j2 + 1] - mrow[mt]);
          asm("v_cvt_pk_bf16_f32 %0, %1, %2" : "=v"(pk[mt][cb][j2]) : "v"(plo), "v"(phi));
        }
    // O += P V : V's kv-order is permuted so lane's own pk registers ARE the A-fragment
#pragma unroll
    for (int kk = 0; kk < 2; ++kk) {
      union { unsigned int u[4]; bf16x8 v; } pa[2];
#pragma unroll
      for (int mt = 0; mt < 2; ++mt) {
        pa[mt].u[0] = pk[mt][2 * kk][0];
        pa[mt].u[1] = pk[mt][2 * kk][1];
        pa[mt].u[2] = pk[mt][2 * kk + 1][0];
        pa[mt].u[3] = pk[mt][2 * kk + 1][1];
      }
#pragma unroll
      for (int cb = 0; cb < 5; ++cb) {
        bf16x8 vb = *(const bf16x8*)&Vt[cb * 16 + q16][kk * 32 + (g << 3)];
#pragma unroll
        for (int mt = 0; mt < 2; ++mt)
          o[mt][cb] = __builtin_amdgcn_mfma_f32_16x16x32_bf16(pa[mt].v, vb, o[mt][cb], 0, 0, 0);
      }
    }
  }
  // epilogue: l = o[.][4] (col 64), broadcast within 4-lane group; scatter untokenized
#pragma unroll
  for (int mt = 0; mt < 2; ++mt)
#pragma unroll
    for (int r = 0; r < 4; ++r) {
      float lr = __shfl(o[mt][4][r], lane & 48);
      float inv = 1.0f / lr;
      int m = (qt << 7) + w * 32 + mt * 16 + (g << 2) + r;
#pragma unroll
      for (int cb = 0; cb < 4; ++cb) {
        int d = (h << 6) + cb * 16 + q16;
        int f = m * 768 + d;
        int c = f >> 18, rl = f & 262143, n = rl >> 8, qq = rl & 255;
        out[((b * 3 + c) << 18) + (((n >> 5) << 4) + (qq >> 4)) * 512 + ((n & 31) << 4) + (qq & 15)] =
            o[mt][cb][r] * inv;
      }
    }
}

extern "C" void kernel_launch(void* const* d_in, const int* in_sizes, int n_in,
                              void* d_out, int out_size, void* d_ws, size_t ws_size,
                              hipStream_t stream) {
  const float* x  = (const float*)d_in[0];
  const float* Wq = (const float*)d_in[1];
  const float* bq = (const float*)d_in[2];
  const float* Wk = (const float*)d_in[3];
  const float* bk = (const float*)d_in[4];
  const float* Wv = (const float*)d_in[5];
  const float* bv = (const float*)d_in[6];
  float* out = (float*)d_out;
  unsigned short* wt = (unsigned short*)d_ws;
  unsigned short* t  = wt + 1769472;
  unsigned short* qw = t  + 12582912;
  unsigned short* kw = qw + 12582912;
  unsigned short* vw = kw + 12582912;
  k_prep_w<<<dim3(36, 12), 256, 0, stream>>>(Wq, Wk, Wv, wt);
  k_build_t<<<1536, 256, 0, stream>>>(x, t);
  k_qkv<<<2304, 256, 0, stream>>>(t, wt, bq, bk, bv, qw, kw, vw);
  k_attn<<<1536, 256, 0, stream>>>(qw, kw, vw, out);
}